// Round 6
// baseline (41.928 us; speedup 1.0000x reference)
//
#include <hip/hip_runtime.h>

#define N_ATOMS 1024
#define N_EDGES 8192
#define EPAD    (N_EDGES + N_ATOMS)   // padded edge capacity (even per-atom lists)
#define NBATCH  256
#define NEG     0.01f

typedef unsigned int u32;
typedef __attribute__((ext_vector_type(2))) float f32x2;
typedef __attribute__((ext_vector_type(4))) float f32x4;
typedef __attribute__((ext_vector_type(8))) _Float16 f16x8;

// pack 2×f32 -> 2×f16 (RTZ), 1 instruction
__device__ __forceinline__ u32 pkrtz(float lo, float hi) {
    u32 r;
    asm("v_cvt_pkrtz_f16_f32 %0, %1, %2" : "=v"(r) : "v"(lo), "v"(hi));
    return r;
}
// acc += w * f16(lo half of u)   /   hi half — single VOP3P v_fma_mix_f32
#define FMIX_LO(a, w, u) \
    asm("v_fma_mix_f32 %0, %1, %2, %0 op_sel_hi:[0,1,0]" : "+v"(a) : "v"(w), "v"(u))
#define FMIX_HI(a, w, u) \
    asm("v_fma_mix_f32 %0, %1, %2, %0 op_sel:[0,1,0] op_sel_hi:[0,1,0]" : "+v"(a) : "v"(w), "v"(u))

// ---------- workspace layout ----------
#define ROWPTR_OFF 0                   // int[1025] (pad 4352)
#define COLW_OFF   4352                // int2[EPAD] = 73728
#define SELFW_OFF  (4352 + 73728)      // float[1024]
#define PERM_OFF   (SELFW_OFF + 4096)  // int[1024]
#define W2T_OFF    (PERM_OFF + 4096)   // u32[2048] f16-pair W2^T = 8192 B

// ---------- LDS layout of main kernel ----------
#define TSTR_B 144                            // tile row stride bytes (64 f16 + pad)
#define SM_TILE_BYTES (N_ATOMS * TSTR_B)      // 147456
#define SM_CT_OFF SM_TILE_BYTES               // ctile4: 1024 float4 = 16384 B
#define SM_TOTAL (SM_TILE_BYTES + 16384)      // 163840 == 160 KiB exactly

// =====================================================================
// Kernel 1: CSR (dst-grouped, even-padded lists) + norm weights +
// degree-sorted permutation + W2^T fp16. 1 block, amortized.
// =====================================================================
__global__ __launch_bounds__(1024) void build_csr(
    const int* __restrict__ ei,
    int*  __restrict__ rowptr,
    int2* __restrict__ colw,
    float* __restrict__ selfw_g,
    int*  __restrict__ perm_g,
    u32*  __restrict__ w2t,
    const float* __restrict__ W2)
{
    __shared__ int   sdeg[N_ATOMS];
    __shared__ int   sstart[N_ATOMS];
    __shared__ float sdinv[N_ATOMS];
    __shared__ int   wtot[16];
    __shared__ int   hist[128];
    const int t = threadIdx.x;
    const int lane = t & 63;
    const int w = t >> 6;
    const int* srcA = ei;
    const int* dstA = ei + N_EDGES;

    sdeg[t] = 0;
    if (t < 128) hist[t] = 0;
    for (int e = t; e < EPAD; e += 1024) colw[e] = make_int2(0, 0);
    __syncthreads();
    for (int e = t; e < N_EDGES; e += 1024) atomicAdd(&sdeg[dstA[e]], 1);
    __syncthreads();

    const int deg  = sdeg[t];
    const int pdeg = (deg + 1) & ~1;          // even-padded length
    int v = pdeg;
    #pragma unroll
    for (int d = 1; d < 64; d <<= 1) {
        int u = __shfl_up(v, d, 64);
        if (lane >= d) v += u;
    }
    if (lane == 63) wtot[w] = v;
    __syncthreads();
    if (t == 0) {
        int run = 0;
        #pragma unroll
        for (int i = 0; i < 16; ++i) { int c = wtot[i]; wtot[i] = run; run += c; }
    }
    __syncthreads();
    const int start = v - pdeg + wtot[w];     // even (all pdeg even)
    sstart[t] = start;
    const float dv = rsqrtf((float)deg + 1.0f);
    sdinv[t] = dv;
    rowptr[t] = start;
    if (t == N_ATOMS - 1) rowptr[N_ATOMS] = start + pdeg;
    selfw_g[t] = dv * dv;

    // W2^T in f16 pairs: w2t[c*32+kk] = pkrtz(W2[2kk][c], W2[2kk+1][c])
    #pragma unroll
    for (int i = 0; i < 2; ++i) {
        const int idx = t + i * 1024;
        const int c = idx >> 5, kk = idx & 31;
        w2t[c * 32 + kk] = pkrtz(W2[(2 * kk) * 64 + c], W2[(2 * kk + 1) * 64 + c]);
    }

    // degree histogram -> counting-sort permutation
    const int dcl = deg < 127 ? deg : 127;
    atomicAdd(&hist[dcl], 1);
    sdeg[t] = 0;   // reuse as fill counters
    __syncthreads();
    if (t == 0) {
        int run = 0;
        for (int i = 0; i < 128; ++i) { int c = hist[i]; hist[i] = run; run += c; }
    }
    __syncthreads();
    const int pos = atomicAdd(&hist[dcl], 1);
    perm_g[pos] = t;
    __syncthreads();

    for (int e = t; e < N_EDGES; e += 1024) {
        const int d = dstA[e];
        const int s = srcA[e];
        const int slot = atomicAdd(&sdeg[d], 1);
        const float wgt = sdinv[s] * sdinv[d];
        colw[sstart[d] + slot] = make_int2(s, __float_as_int(wgt));
    }
}

// =====================================================================
// Kernel 2: fused GCN x2 + mean-pool + project. 1 block per molecule.
// Phase 2: 8 lanes per atom, 1 chunk (8 feats) per lane -> bank-uniform
// ds_read_b128 gather, balanced trip counts.
// =====================================================================
__global__ __launch_bounds__(1024, 4) void gnn_main(
    const float* __restrict__ x,
    const int*  __restrict__ rowptr,
    const int2* __restrict__ colw,
    const float* __restrict__ selfw_g,
    const int*  __restrict__ perm_g,
    const float* __restrict__ W1, const float* __restrict__ b1,
    const u32*  __restrict__ w2t, const float* __restrict__ b2,
    const float* __restrict__ Wp, const float* __restrict__ bp,
    float* __restrict__ out)
{
    extern __shared__ char smem[];
    float4* ctile4 = (float4*)(smem + SM_CT_OFF);  // [1024] coords xyz_ (ph 0/1)
    float*  paux   = (float*)ctile4;               // aliased post-phase-1:
    float*  wpool  = paux;                         //   [16][64] floats
    float*  gvec   = paux + 1024;                  //   [64]
    float*  proj   = paux + 1088;                  //   [4][128]
    int*    satom  = (int*)(paux + 1600);          //   [1024] wave-row atom ids

    const int t = threadIdx.x;
    const int b = blockIdx.x;
    const float* xb = x + (size_t)b * (3 * N_ATOMS);

    // ---- phase 0: coords -> ctile4 ----
    {
        float4 c;
        c.x = xb[3 * t]; c.y = xb[3 * t + 1]; c.z = xb[3 * t + 2]; c.w = 0.0f;
        ctile4[t] = c;
    }
    __syncthreads();

    // ---- phase 1: aggregate coords, GEMM1 + leaky -> fp16 tile (per-thread atom) ----
    {
        const int atom = perm_g[t];
        const int s0 = rowptr[atom], s1 = rowptr[atom + 1];
        const float sw = selfw_g[atom];
        const float4 cs = ctile4[atom];
        float A0 = sw * cs.x, A1 = sw * cs.y, A2 = sw * cs.z;
        int4 cur = make_int4(0, 0, 0, 0);
        if (s0 < s1) cur = *(const int4*)(colw + s0);
        for (int j = s0; j < s1; j += 2) {
            const int jn = (j + 2 < s1) ? (j + 2) : s0;
            const int4 nxt = *(const int4*)(colw + jn);    // prefetch
            const float4 c0 = ctile4[cur.x];
            const float4 c1 = ctile4[cur.z];
            const float w0 = __int_as_float(cur.y), w1 = __int_as_float(cur.w);
            A0 += w0 * c0.x + w1 * c1.x;
            A1 += w0 * c0.y + w1 * c1.y;
            A2 += w0 * c0.z + w1 * c1.z;
            cur = nxt;
        }
        u32 pw[32];
        #pragma unroll
        for (int p = 0; p < 32; ++p) {
            f32x2 vv = *(const f32x2*)(b1 + 2 * p);
            vv = __builtin_elementwise_fma((f32x2){A0, A0}, *(const f32x2*)(W1 + 2 * p), vv);
            vv = __builtin_elementwise_fma((f32x2){A1, A1}, *(const f32x2*)(W1 + 64 + 2 * p), vv);
            vv = __builtin_elementwise_fma((f32x2){A2, A2}, *(const f32x2*)(W1 + 128 + 2 * p), vv);
            vv.x = fmaxf(vv.x, NEG * vv.x);
            vv.y = fmaxf(vv.y, NEG * vv.y);
            pw[p] = pkrtz(vv.x, vv.y);
        }
        uint4* trow = (uint4*)(smem + (size_t)atom * TSTR_B);
        #pragma unroll
        for (int q = 0; q < 8; ++q)
            trow[q] = make_uint4(pw[4 * q], pw[4 * q + 1], pw[4 * q + 2], pw[4 * q + 3]);
    }
    __syncthreads();

    // ---- phase 2: gather h1. Lane (g,m): g=lane>>3 owns atoms, m=lane&7 owns
    //      16B chunk. Round k: atom = perm[k*128 + w*8 + g]. Bank-uniform. ----
    const int w   = t >> 6;
    const int g   = (t & 63) >> 3;
    const int m   = t & 7;
    const int mo  = m * 16;                     // chunk byte offset in row

    int atoms[8];
    #pragma unroll
    for (int k = 0; k < 8; ++k) atoms[k] = perm_g[k * 128 + w * 8 + g];
    int s0a[8], s1a[8];
    #pragma unroll
    for (int k = 0; k < 8; ++k) {
        s0a[k] = rowptr[atoms[k]];
        s1a[k] = rowptr[atoms[k] + 1];
    }

    u32 pr[8][4];
    #pragma unroll
    for (int k = 0; k < 8; ++k) {
        const int atom = atoms[k];
        float acc[8];
        #pragma unroll
        for (int f = 0; f < 8; ++f) acc[f] = 0.0f;
        // self-loop term from tile
        {
            const float swk = selfw_g[atom];
            const uint4 sv = *(const uint4*)(smem + (size_t)atom * TSTR_B + mo);
            FMIX_LO(acc[0], swk, sv.x); FMIX_HI(acc[1], swk, sv.x);
            FMIX_LO(acc[2], swk, sv.y); FMIX_HI(acc[3], swk, sv.y);
            FMIX_LO(acc[4], swk, sv.z); FMIX_HI(acc[5], swk, sv.z);
            FMIX_LO(acc[6], swk, sv.w); FMIX_HI(acc[7], swk, sv.w);
        }
        for (int j = s0a[k]; j < s1a[k]; j += 2) {
            const int4 cw = *(const int4*)(colw + j);      // 8 lanes same addr
            const uint4 qA = *(const uint4*)(smem + (size_t)cw.x * TSTR_B + mo);
            const uint4 qB = *(const uint4*)(smem + (size_t)cw.z * TSTR_B + mo);
            const float wA = __int_as_float(cw.y);
            const float wB = __int_as_float(cw.w);
            FMIX_LO(acc[0], wA, qA.x); FMIX_HI(acc[1], wA, qA.x);
            FMIX_LO(acc[2], wA, qA.y); FMIX_HI(acc[3], wA, qA.y);
            FMIX_LO(acc[4], wA, qA.z); FMIX_HI(acc[5], wA, qA.z);
            FMIX_LO(acc[6], wA, qA.w); FMIX_HI(acc[7], wA, qA.w);
            FMIX_LO(acc[0], wB, qB.x); FMIX_HI(acc[1], wB, qB.x);
            FMIX_LO(acc[2], wB, qB.y); FMIX_HI(acc[3], wB, qB.y);
            FMIX_LO(acc[4], wB, qB.z); FMIX_HI(acc[5], wB, qB.z);
            FMIX_LO(acc[6], wB, qB.w); FMIX_HI(acc[7], wB, qB.w);
        }
        pr[k][0] = pkrtz(acc[0], acc[1]);
        pr[k][1] = pkrtz(acc[2], acc[3]);
        pr[k][2] = pkrtz(acc[4], acc[5]);
        pr[k][3] = pkrtz(acc[6], acc[7]);
    }
    __syncthreads();   // ALL gathers done -> safe to overwrite tile

    // writeback agg chunks (bank-uniform) + satom table
    #pragma unroll
    for (int k = 0; k < 8; ++k) {
        *(uint4*)(smem + (size_t)atoms[k] * TSTR_B + mo) =
            make_uint4(pr[k][0], pr[k][1], pr[k][2], pr[k][3]);
    }
    if (m == 0) {
        #pragma unroll
        for (int k = 0; k < 8; ++k) satom[w * 64 + k * 8 + g] = atoms[k];
    }
    __syncthreads();

    // ---- phase 3: GEMM2 via MFMA f16 + bias + leaky + pool ----
    {
        const int l15 = t & 15;
        const int lq  = (t & 63) >> 4;

        f16x8 wf[2][4];
        #pragma unroll
        for (int kt = 0; kt < 2; ++kt)
            #pragma unroll
            for (int ct = 0; ct < 4; ++ct)
                wf[kt][ct] = *(const f16x8*)(w2t + (ct * 16 + l15) * 32 + kt * 16 + lq * 4);
        float bias[4];
        #pragma unroll
        for (int ct = 0; ct < 4; ++ct) bias[ct] = b2[ct * 16 + l15];

        float pool[4] = {0.f, 0.f, 0.f, 0.f};
        #pragma unroll
        for (int rt = 0; rt < 4; ++rt) {
            const int arow = satom[w * 64 + rt * 16 + l15];
            const char* ab = smem + (size_t)arow * TSTR_B + lq * 16;
            const f16x8 a0 = *(const f16x8*)(ab);
            const f16x8 a1 = *(const f16x8*)(ab + 64);
            #pragma unroll
            for (int ct = 0; ct < 4; ++ct) {
                f32x4 cf = {0.f, 0.f, 0.f, 0.f};
                cf = __builtin_amdgcn_mfma_f32_16x16x32_f16(a0, wf[0][ct], cf, 0, 0, 0);
                cf = __builtin_amdgcn_mfma_f32_16x16x32_f16(a1, wf[1][ct], cf, 0, 0, 0);
                float s = 0.0f;
                #pragma unroll
                for (int r = 0; r < 4; ++r) {
                    const float vv = cf[r] + bias[ct];
                    s += fmaxf(vv, NEG * vv);
                }
                pool[ct] += s;
            }
        }
        #pragma unroll
        for (int ct = 0; ct < 4; ++ct) {
            pool[ct] += __shfl_xor(pool[ct], 16, 64);
            pool[ct] += __shfl_xor(pool[ct], 32, 64);
        }
        if ((t & 63) < 16) {
            #pragma unroll
            for (int ct = 0; ct < 4; ++ct)
                wpool[w * 64 + ct * 16 + l15] = pool[ct];
        }
    }
    __syncthreads();

    // ---- final pool + project ----
    if (t < 64) {
        float s = 0.0f;
        #pragma unroll
        for (int ww = 0; ww < 16; ++ww) s += wpool[ww * 64 + t];
        gvec[t] = s * (1.0f / 1024.0f);
    }
    __syncthreads();
    if (t < 512) {
        const int col = t & 127, pc = t >> 7;
        float s = 0.0f;
        #pragma unroll
        for (int f = 0; f < 16; ++f)
            s += gvec[pc * 16 + f] * Wp[(pc * 16 + f) * 128 + col];
        proj[pc * 128 + col] = s;
    }
    __syncthreads();
    if (t < 128) {
        float s = bp[t] + proj[t] + proj[128 + t] + proj[256 + t] + proj[384 + t];
        s = fmaxf(s, NEG * s);
        out[(size_t)b * 128 + t] = s;
    }
}

// =====================================================================
extern "C" void kernel_launch(void* const* d_in, const int* in_sizes, int n_in,
                              void* d_out, int out_size, void* d_ws, size_t ws_size,
                              hipStream_t stream) {
    const float* x  = (const float*)d_in[0];
    const int*   ei = (const int*)  d_in[1];
    const float* W1 = (const float*)d_in[2];
    const float* b1 = (const float*)d_in[3];
    const float* W2 = (const float*)d_in[4];
    const float* b2 = (const float*)d_in[5];
    const float* Wp = (const float*)d_in[6];
    const float* bp = (const float*)d_in[7];
    float* out = (float*)d_out;

    char* ws = (char*)d_ws;
    int*   rowptr = (int*)  (ws + ROWPTR_OFF);
    int2*  colw   = (int2*) (ws + COLW_OFF);
    float* selfw  = (float*)(ws + SELFW_OFF);
    int*   perm   = (int*)  (ws + PERM_OFF);
    u32*   w2t    = (u32*)  (ws + W2T_OFF);

    build_csr<<<1, 1024, 0, stream>>>(ei, rowptr, colw, selfw, perm, w2t, W2);

    (void)hipFuncSetAttribute((const void*)gnn_main,
                              hipFuncAttributeMaxDynamicSharedMemorySize, SM_TOTAL);
    gnn_main<<<NBATCH, 1024, SM_TOTAL, stream>>>(
        x, rowptr, colw, selfw, perm, W1, b1, w2t, b2, Wp, bp, out);
}

// Round 7
// 41.678 us; speedup vs baseline: 1.0060x; 1.0060x over previous
//
#include <hip/hip_runtime.h>

#define N_ATOMS 1024
#define N_EDGES 8192
#define EPAD    (N_EDGES + N_ATOMS)   // padded edge capacity (even per-atom lists)
#define NBATCH  256
#define NEG     0.01f

typedef unsigned int u32;
typedef __attribute__((ext_vector_type(2))) float f32x2;
typedef __attribute__((ext_vector_type(4))) float f32x4;
typedef __attribute__((ext_vector_type(8))) _Float16 f16x8;

// pack 2×f32 -> 2×f16 (RTZ), 1 instruction
__device__ __forceinline__ u32 pkrtz(float lo, float hi) {
    u32 r;
    asm("v_cvt_pkrtz_f16_f32 %0, %1, %2" : "=v"(r) : "v"(lo), "v"(hi));
    return r;
}
// acc += w * f16(lo half of u)   /   hi half — single VOP3P v_fma_mix_f32
#define FMIX_LO(a, w, u) \
    asm("v_fma_mix_f32 %0, %1, %2, %0 op_sel_hi:[0,1,0]" : "+v"(a) : "v"(w), "v"(u))
#define FMIX_HI(a, w, u) \
    asm("v_fma_mix_f32 %0, %1, %2, %0 op_sel:[0,1,0] op_sel_hi:[0,1,0]" : "+v"(a) : "v"(w), "v"(u))

// ---------- workspace layout ----------
#define ROWPTR_OFF 0                   // int[1025] (pad 4352)
#define COLW_OFF   4352                // int2[EPAD] = 73728
#define SELFW_OFF  (4352 + 73728)      // float[1024]
#define PERM_OFF   (SELFW_OFF + 4096)  // int[1024]
#define W2T_OFF    (PERM_OFF + 4096)   // u32[2048] f16-pair W2^T = 8192 B

// ---------- LDS layout of main kernel ----------
#define TSTR_B 144                            // tile row stride bytes (64 f16 + pad)
#define SM_TILE_BYTES (N_ATOMS * TSTR_B)      // 147456
#define SM_CT_OFF SM_TILE_BYTES               // ctile4: 1024 float4 = 16384 B
#define SM_TOTAL (SM_TILE_BYTES + 16384)      // 163840 == 160 KiB exactly

// =====================================================================
// Kernel 1: CSR (dst-grouped, even-padded lists) + norm weights +
// degree-sorted permutation + W2^T fp16. 1 block, amortized.
// =====================================================================
__global__ __launch_bounds__(1024) void build_csr(
    const int* __restrict__ ei,
    int*  __restrict__ rowptr,
    int2* __restrict__ colw,
    float* __restrict__ selfw_g,
    int*  __restrict__ perm_g,
    u32*  __restrict__ w2t,
    const float* __restrict__ W2)
{
    __shared__ int   sdeg[N_ATOMS];
    __shared__ int   sstart[N_ATOMS];
    __shared__ float sdinv[N_ATOMS];
    __shared__ int   wtot[16];
    __shared__ int   hist[128];
    const int t = threadIdx.x;
    const int lane = t & 63;
    const int w = t >> 6;
    const int* srcA = ei;
    const int* dstA = ei + N_EDGES;

    sdeg[t] = 0;
    if (t < 128) hist[t] = 0;
    __syncthreads();
    for (int e = t; e < N_EDGES; e += 1024) atomicAdd(&sdeg[dstA[e]], 1);
    __syncthreads();

    const int deg  = sdeg[t];
    const int pdeg = (deg + 1) & ~1;          // even-padded length
    int v = pdeg;
    #pragma unroll
    for (int d = 1; d < 64; d <<= 1) {
        int u = __shfl_up(v, d, 64);
        if (lane >= d) v += u;
    }
    if (lane == 63) wtot[w] = v;
    __syncthreads();
    if (t == 0) {
        int run = 0;
        #pragma unroll
        for (int i = 0; i < 16; ++i) { int c = wtot[i]; wtot[i] = run; run += c; }
    }
    __syncthreads();
    const int start = v - pdeg + wtot[w];     // even (all pdeg even)
    sstart[t] = start;
    const float dv = rsqrtf((float)deg + 1.0f);
    sdinv[t] = dv;
    rowptr[t] = start;
    if (t == N_ATOMS - 1) rowptr[N_ATOMS] = start + pdeg;
    selfw_g[t] = dv * dv;
    // pad slot for odd-degree atoms: contributes 0 (src 0, weight 0)
    if (deg & 1) colw[start + deg] = make_int2(0, 0);

    // W2^T in f16 pairs: w2t[c*32+kk] = pkrtz(W2[2kk][c], W2[2kk+1][c])
    #pragma unroll
    for (int i = 0; i < 2; ++i) {
        const int idx = t + i * 1024;
        const int c = idx >> 5, kk = idx & 31;
        w2t[c * 32 + kk] = pkrtz(W2[(2 * kk) * 64 + c], W2[(2 * kk + 1) * 64 + c]);
    }

    // degree histogram -> counting-sort permutation
    const int dcl = deg < 127 ? deg : 127;
    atomicAdd(&hist[dcl], 1);
    sdeg[t] = 0;   // reuse as fill counters
    __syncthreads();
    if (t == 0) {
        int run = 0;
        for (int i = 0; i < 128; ++i) { int c = hist[i]; hist[i] = run; run += c; }
    }
    __syncthreads();
    const int pos = atomicAdd(&hist[dcl], 1);
    perm_g[pos] = t;
    __syncthreads();

    for (int e = t; e < N_EDGES; e += 1024) {
        const int d = dstA[e];
        const int s = srcA[e];
        const int slot = atomicAdd(&sdeg[d], 1);
        const float wgt = sdinv[s] * sdinv[d];
        colw[sstart[d] + slot] = make_int2(s, __float_as_int(wgt));
    }
}

// =====================================================================
// Kernel 2: fused GCN x2 + mean-pool + project. 1 block per molecule.
// Phase 2: 8 lanes per atom (bank-uniform chunks), 4 atoms fused per
// lane per pass (MLP: 4 VMEM + 8 LDS reads + 64 FMIX per iteration).
// =====================================================================
__global__ __launch_bounds__(1024, 4) void gnn_main(
    const float* __restrict__ x,
    const int*  __restrict__ rowptr,
    const int2* __restrict__ colw,
    const float* __restrict__ selfw_g,
    const int*  __restrict__ perm_g,
    const float* __restrict__ W1, const float* __restrict__ b1,
    const u32*  __restrict__ w2t, const float* __restrict__ b2,
    const float* __restrict__ Wp, const float* __restrict__ bp,
    float* __restrict__ out)
{
    extern __shared__ char smem[];
    float4* ctile4 = (float4*)(smem + SM_CT_OFF);  // [1024] coords xyz_ (ph 0/1)
    float*  paux   = (float*)ctile4;               // aliased post-phase-1:
    float*  wpool  = paux;                         //   [16][64] floats
    float*  gvec   = paux + 1024;                  //   [64]
    float*  proj   = paux + 1088;                  //   [4][128]
    int*    satom  = (int*)(paux + 1600);          //   [1024] wave-row atom ids

    const int t = threadIdx.x;
    const int b = blockIdx.x;
    const float* xb = x + (size_t)b * (3 * N_ATOMS);

    // ---- phase 0: coords -> ctile4 ----
    {
        float4 c;
        c.x = xb[3 * t]; c.y = xb[3 * t + 1]; c.z = xb[3 * t + 2]; c.w = 0.0f;
        ctile4[t] = c;
    }
    __syncthreads();

    // ---- phase 1: aggregate coords, GEMM1 + leaky -> fp16 tile ----
    {
        const int atom = perm_g[t];
        const int s0 = rowptr[atom], s1 = rowptr[atom + 1];
        const float sw = selfw_g[atom];
        const float4 cs = ctile4[atom];
        float A0 = sw * cs.x, A1 = sw * cs.y, A2 = sw * cs.z;
        int4 cur = make_int4(0, 0, 0, 0);
        if (s0 < s1) cur = *(const int4*)(colw + s0);
        for (int j = s0; j < s1; j += 2) {
            const int jn = (j + 2 < s1) ? (j + 2) : s0;
            const int4 nxt = *(const int4*)(colw + jn);    // prefetch
            const float4 c0 = ctile4[cur.x];
            const float4 c1 = ctile4[cur.z];
            const float w0 = __int_as_float(cur.y), w1 = __int_as_float(cur.w);
            A0 += w0 * c0.x + w1 * c1.x;
            A1 += w0 * c0.y + w1 * c1.y;
            A2 += w0 * c0.z + w1 * c1.z;
            cur = nxt;
        }
        u32 pw[32];
        #pragma unroll
        for (int p = 0; p < 32; ++p) {
            f32x2 vv = *(const f32x2*)(b1 + 2 * p);
            vv = __builtin_elementwise_fma((f32x2){A0, A0}, *(const f32x2*)(W1 + 2 * p), vv);
            vv = __builtin_elementwise_fma((f32x2){A1, A1}, *(const f32x2*)(W1 + 64 + 2 * p), vv);
            vv = __builtin_elementwise_fma((f32x2){A2, A2}, *(const f32x2*)(W1 + 128 + 2 * p), vv);
            vv.x = fmaxf(vv.x, NEG * vv.x);
            vv.y = fmaxf(vv.y, NEG * vv.y);
            pw[p] = pkrtz(vv.x, vv.y);
        }
        uint4* trow = (uint4*)(smem + (size_t)atom * TSTR_B);
        #pragma unroll
        for (int q = 0; q < 8; ++q)
            trow[q] = make_uint4(pw[4 * q], pw[4 * q + 1], pw[4 * q + 2], pw[4 * q + 3]);
    }

    // phase-2 setup (global reads; legal before the barrier)
    const int w   = t >> 6;
    const int g   = (t & 63) >> 3;
    const int m   = t & 7;
    const int mo  = m * 16;                     // chunk byte offset in row

    int atoms[8], s0a[8], npa[8];
    float swa[8];
    #pragma unroll
    for (int k = 0; k < 8; ++k) {
        atoms[k] = perm_g[k * 128 + w * 8 + g];
        const int r0 = rowptr[atoms[k]];
        const int r1 = rowptr[atoms[k] + 1];
        s0a[k] = r0;
        npa[k] = (r1 - r0) >> 1;
        swa[k] = selfw_g[atoms[k]];
    }
    __syncthreads();

    // ---- phase 2: gather h1; 2 passes × 4 fused atoms ----
    u32 pr[8][4];
    #pragma unroll
    for (int p = 0; p < 2; ++p) {
        float acc[32];
        #pragma unroll
        for (int f = 0; f < 32; ++f) acc[f] = 0.0f;
        // self-loop terms (4 independent LDS reads)
        #pragma unroll
        for (int k = 0; k < 4; ++k) {
            const uint4 sv = *(const uint4*)(smem + (size_t)atoms[p*4+k] * TSTR_B + mo);
            const float swk = swa[p*4+k];
            FMIX_LO(acc[k*8+0], swk, sv.x); FMIX_HI(acc[k*8+1], swk, sv.x);
            FMIX_LO(acc[k*8+2], swk, sv.y); FMIX_HI(acc[k*8+3], swk, sv.y);
            FMIX_LO(acc[k*8+4], swk, sv.z); FMIX_HI(acc[k*8+5], swk, sv.z);
            FMIX_LO(acc[k*8+6], swk, sv.w); FMIX_HI(acc[k*8+7], swk, sv.w);
        }
        const int mx = max(max(npa[p*4+0], npa[p*4+1]), max(npa[p*4+2], npa[p*4+3]));
        for (int jj = 0; jj < mx; ++jj) {
            #pragma unroll
            for (int k = 0; k < 4; ++k) {
                if (jj < npa[p*4+k]) {
                    const int4 cw = *(const int4*)(colw + s0a[p*4+k] + 2*jj);
                    const uint4 qA = *(const uint4*)(smem + (size_t)cw.x * TSTR_B + mo);
                    const uint4 qB = *(const uint4*)(smem + (size_t)cw.z * TSTR_B + mo);
                    const float wA = __int_as_float(cw.y);
                    const float wB = __int_as_float(cw.w);
                    FMIX_LO(acc[k*8+0], wA, qA.x); FMIX_HI(acc[k*8+1], wA, qA.x);
                    FMIX_LO(acc[k*8+2], wA, qA.y); FMIX_HI(acc[k*8+3], wA, qA.y);
                    FMIX_LO(acc[k*8+4], wA, qA.z); FMIX_HI(acc[k*8+5], wA, qA.z);
                    FMIX_LO(acc[k*8+6], wA, qA.w); FMIX_HI(acc[k*8+7], wA, qA.w);
                    FMIX_LO(acc[k*8+0], wB, qB.x); FMIX_HI(acc[k*8+1], wB, qB.x);
                    FMIX_LO(acc[k*8+2], wB, qB.y); FMIX_HI(acc[k*8+3], wB, qB.y);
                    FMIX_LO(acc[k*8+4], wB, qB.z); FMIX_HI(acc[k*8+5], wB, qB.z);
                    FMIX_LO(acc[k*8+6], wB, qB.w); FMIX_HI(acc[k*8+7], wB, qB.w);
                }
            }
        }
        #pragma unroll
        for (int k = 0; k < 4; ++k) {
            pr[p*4+k][0] = pkrtz(acc[k*8+0], acc[k*8+1]);
            pr[p*4+k][1] = pkrtz(acc[k*8+2], acc[k*8+3]);
            pr[p*4+k][2] = pkrtz(acc[k*8+4], acc[k*8+5]);
            pr[p*4+k][3] = pkrtz(acc[k*8+6], acc[k*8+7]);
        }
    }

    // phase-3 weight fragments: issue global loads before the barrier
    const int l15 = t & 15;
    const int lq  = (t & 63) >> 4;
    f16x8 wf[2][4];
    #pragma unroll
    for (int kt = 0; kt < 2; ++kt)
        #pragma unroll
        for (int ct = 0; ct < 4; ++ct)
            wf[kt][ct] = *(const f16x8*)(w2t + (ct * 16 + l15) * 32 + kt * 16 + lq * 4);
    float bias[4];
    #pragma unroll
    for (int ct = 0; ct < 4; ++ct) bias[ct] = b2[ct * 16 + l15];

    __syncthreads();   // ALL gathers done -> safe to overwrite tile

    // writeback agg chunks (bank-uniform) + satom table
    #pragma unroll
    for (int k = 0; k < 8; ++k) {
        *(uint4*)(smem + (size_t)atoms[k] * TSTR_B + mo) =
            make_uint4(pr[k][0], pr[k][1], pr[k][2], pr[k][3]);
    }
    if (m == 0) {
        #pragma unroll
        for (int k = 0; k < 8; ++k) satom[w * 64 + k * 8 + g] = atoms[k];
    }
    __syncthreads();

    // ---- phase 3: GEMM2 via MFMA f16 + bias + leaky + pool ----
    {
        float pool[4] = {0.f, 0.f, 0.f, 0.f};
        #pragma unroll
        for (int rt = 0; rt < 4; ++rt) {
            const int arow = satom[w * 64 + rt * 16 + l15];
            const char* ab = smem + (size_t)arow * TSTR_B + lq * 16;
            const f16x8 a0 = *(const f16x8*)(ab);
            const f16x8 a1 = *(const f16x8*)(ab + 64);
            #pragma unroll
            for (int ct = 0; ct < 4; ++ct) {
                f32x4 cf = {0.f, 0.f, 0.f, 0.f};
                cf = __builtin_amdgcn_mfma_f32_16x16x32_f16(a0, wf[0][ct], cf, 0, 0, 0);
                cf = __builtin_amdgcn_mfma_f32_16x16x32_f16(a1, wf[1][ct], cf, 0, 0, 0);
                float s = 0.0f;
                #pragma unroll
                for (int r = 0; r < 4; ++r) {
                    const float vv = cf[r] + bias[ct];
                    s += fmaxf(vv, NEG * vv);
                }
                pool[ct] += s;
            }
        }
        #pragma unroll
        for (int ct = 0; ct < 4; ++ct) {
            pool[ct] += __shfl_xor(pool[ct], 16, 64);
            pool[ct] += __shfl_xor(pool[ct], 32, 64);
        }
        if ((t & 63) < 16) {
            #pragma unroll
            for (int ct = 0; ct < 4; ++ct)
                wpool[w * 64 + ct * 16 + l15] = pool[ct];
        }
    }
    __syncthreads();

    // ---- final pool + project ----
    if (t < 64) {
        float s = 0.0f;
        #pragma unroll
        for (int ww = 0; ww < 16; ++ww) s += wpool[ww * 64 + t];
        gvec[t] = s * (1.0f / 1024.0f);
    }
    __syncthreads();
    if (t < 512) {
        const int col = t & 127, pc = t >> 7;
        float s = 0.0f;
        #pragma unroll
        for (int f = 0; f < 16; ++f)
            s += gvec[pc * 16 + f] * Wp[(pc * 16 + f) * 128 + col];
        proj[pc * 128 + col] = s;
    }
    __syncthreads();
    if (t < 128) {
        float s = bp[t] + proj[t] + proj[128 + t] + proj[256 + t] + proj[384 + t];
        s = fmaxf(s, NEG * s);
        out[(size_t)b * 128 + t] = s;
    }
}

// =====================================================================
extern "C" void kernel_launch(void* const* d_in, const int* in_sizes, int n_in,
                              void* d_out, int out_size, void* d_ws, size_t ws_size,
                              hipStream_t stream) {
    const float* x  = (const float*)d_in[0];
    const int*   ei = (const int*)  d_in[1];
    const float* W1 = (const float*)d_in[2];
    const float* b1 = (const float*)d_in[3];
    const float* W2 = (const float*)d_in[4];
    const float* b2 = (const float*)d_in[5];
    const float* Wp = (const float*)d_in[6];
    const float* bp = (const float*)d_in[7];
    float* out = (float*)d_out;

    char* ws = (char*)d_ws;
    int*   rowptr = (int*)  (ws + ROWPTR_OFF);
    int2*  colw   = (int2*) (ws + COLW_OFF);
    float* selfw  = (float*)(ws + SELFW_OFF);
    int*   perm   = (int*)  (ws + PERM_OFF);
    u32*   w2t    = (u32*)  (ws + W2T_OFF);

    build_csr<<<1, 1024, 0, stream>>>(ei, rowptr, colw, selfw, perm, w2t, W2);

    (void)hipFuncSetAttribute((const void*)gnn_main,
                              hipFuncAttributeMaxDynamicSharedMemorySize, SM_TOTAL);
    gnn_main<<<NBATCH, 1024, SM_TOTAL, stream>>>(
        x, rowptr, colw, selfw, perm, W1, b1, w2t, b2, Wp, bp, out);
}